// Round 2
// 137.511 us; speedup vs baseline: 1.0746x; 1.0746x over previous
//
#include <hip/hip_runtime.h>
#include <hip/hip_bf16.h>

#define BSZ 256
#define ADIM 128
#define HID 512
#define MT 64          // pair-rows per block
#define LDH 520        // padded LDS row stride in bf16 elements

typedef __attribute__((ext_vector_type(8))) short short8;
typedef __attribute__((ext_vector_type(4))) float float4_t;
typedef __attribute__((ext_vector_type(4))) unsigned uint4_t;

__device__ inline short f32_to_bf16_bits(float f) {
    union { float f; unsigned u; } v; v.f = f;
    unsigned u = v.u;
    unsigned r = u + 0x7FFFu + ((u >> 16) & 1u);   // RNE
    return (short)(r >> 16);
}

// packed RNE f32x2 -> bf16x2 (no builtin on gfx950; inline asm per guide)
__device__ __forceinline__ unsigned cvt_pk_bf16(float lo, float hi) {
    unsigned r;
    asm("v_cvt_pk_bf16_f32 %0, %1, %2" : "=v"(r) : "v"(lo), "v"(hi));
    return r;
}

// ---------------- prep (256 blocks x 512 threads) ----------------
// blocks [0,64):    hx = x@Wx + b0   (4 rows per block)
// blocks [64,128):  hy = y@Wy        (4 rows per block)
// blocks [128,192): W1p = fragment-packed bf16 of W1 (64x64 tile per block)
// blocks [192,256): W2p = fragment-packed bf16 of W2
// Packed layout: Wp[((s*32+g)*64 + lane)*8 + j] = W[s*32 + (lane>>4)*8 + j][g*16 + (lane&15)]
__global__ __launch_bounds__(512) void prep_kernel(
        const float* __restrict__ x, const float* __restrict__ y,
        const float* __restrict__ Wx, const float* __restrict__ Wy,
        const float* __restrict__ b0, const float* __restrict__ W1,
        const float* __restrict__ W2,
        float* __restrict__ hx, float* __restrict__ hy,
        short* __restrict__ W1p, short* __restrict__ W2p) {
    __shared__ float lds[64 * 65];
    const int tid = threadIdx.x;
    const int bid = blockIdx.x;

    if (bid < 128) {
        const bool isX = bid < 64;
        const int i0 = (isX ? bid : bid - 64) * 4;
        const float* src = isX ? x : y;
        const float* W   = isX ? Wx : Wy;
        float* dst       = isX ? hx : hy;

        // x/y row values are wave-uniform (no tid in address) -> compiler
        // emits scalar (SMEM) loads; no LDS pipe traffic at all.
        const int h = tid;
        const float* r0 = src + i0 * ADIM;
        float s0 = 0.f, s1 = 0.f, s2 = 0.f, s3 = 0.f;
        const float* wcol = W + h;
        #pragma unroll 8
        for (int k = 0; k < ADIM; ++k) {
            float w = wcol[k * HID];
            s0 = fmaf(r0[k], w, s0);
            s1 = fmaf(r0[ADIM + k], w, s1);
            s2 = fmaf(r0[2 * ADIM + k], w, s2);
            s3 = fmaf(r0[3 * ADIM + k], w, s3);
        }
        float bb = isX ? b0[h] : 0.f;
        dst[(i0 + 0) * HID + h] = s0 + bb;
        dst[(i0 + 1) * HID + h] = s1 + bb;
        dst[(i0 + 2) * HID + h] = s2 + bb;
        dst[(i0 + 3) * HID + h] = s3 + bb;
    } else {
        const int tb = bid - 128;
        const bool is1 = tb < 64;
        const int t8 = is1 ? tb : tb - 64;
        const float* Wsrc = is1 ? W1 : W2;
        short* Wdst = is1 ? W1p : W2p;
        const int k0 = (t8 >> 3) * 64;      // source k block
        const int n0 = (t8 & 7) * 64;       // source n block

        // load + transpose 64x64 f32 tile into LDS: lds[n*65 + k]
        #pragma unroll
        for (int i = 0; i < 8; ++i) {
            int r = (tid >> 6) + i * 8;     // k within tile
            int c = tid & 63;               // n within tile (coalesced)
            lds[c * 65 + r] = Wsrc[(k0 + r) * HID + n0 + c];
        }
        __syncthreads();

        // write fragment-packed: thread t -> one 16B chunk
        const int local_s = tid >> 8;           // 0..1
        const int g_local = (tid >> 6) & 3;     // 0..3
        const int lane    = tid & 63;
        const int quad    = lane >> 4;
        const int lq      = lane & 15;
        const int s_glob  = (t8 >> 3) * 2 + local_s;   // 0..15
        const int g_glob  = (t8 & 7) * 4 + g_local;    // 0..31

        const float* srcp = lds + (g_local * 16 + lq) * 65 + local_s * 32 + quad * 8;
        short8 v;
        #pragma unroll
        for (int j = 0; j < 8; ++j) v[j] = f32_to_bf16_bits(srcp[j]);
        *(short8*)(Wdst + ((s_glob * 32 + g_glob) * 64 + lane) * 8) = v;
    }
}

// ---------------- fused layer: wave computes 64(M) x 64(N) chunk ----------------
__device__ __forceinline__ void gemm_layer(short* __restrict__ hs,
                                           const short* __restrict__ Wp,
                                           const float* __restrict__ bias,
                                           int wave, int lane) {
    const int quad = lane >> 4;
    const int lq = lane & 15;
    const int n0 = wave * 64;

    float4_t acc[4][4];
    #pragma unroll
    for (int mi = 0; mi < 4; ++mi)
        #pragma unroll
        for (int ni = 0; ni < 4; ++ni)
            acc[mi][ni] = (float4_t){0.f, 0.f, 0.f, 0.f};

    const short* pb = Wp + wave * 2048 + lane * 8;     // + ni*512 + s*16384
    const short* abase = hs + lq * LDH + quad * 8;

    short8 bf[2][4];
    #pragma unroll
    for (int ni = 0; ni < 4; ++ni)
        bf[0][ni] = *(const short8*)(pb + ni * 512);

    // pointer-chained prefetch base: each step's 4 loads use imm offsets
    const short* ps = pb + 16384;

    #pragma unroll
    for (int s = 0; s < 16; ++s) {
        const int cur = s & 1;
        if (s < 15) {
            #pragma unroll
            for (int ni = 0; ni < 4; ++ni)
                bf[cur ^ 1][ni] = *(const short8*)(ps + ni * 512);
            ps += 16384;
        }
        short8 af[4];
        #pragma unroll
        for (int mi = 0; mi < 4; ++mi)
            af[mi] = *(const short8*)(abase + mi * 16 * LDH + s * 32);
        __builtin_amdgcn_s_setprio(1);
        #pragma unroll
        for (int mi = 0; mi < 4; ++mi)
            #pragma unroll
            for (int ni = 0; ni < 4; ++ni)
                acc[mi][ni] = __builtin_amdgcn_mfma_f32_16x16x32_bf16(
                    af[mi], bf[cur][ni], acc[mi][ni], 0, 0, 0);
        __builtin_amdgcn_s_setprio(0);
    }

    float bv[4];
    #pragma unroll
    for (int ni = 0; ni < 4; ++ni) bv[ni] = bias[n0 + ni * 16 + lq];

    __syncthreads();   // all reads of hs complete before overwrite

    // epilogue: bias+relu, packed RNE cvt (2 elems/instr), b16 lo/hi stores
    #pragma unroll
    for (int ni = 0; ni < 4; ++ni) {
        #pragma unroll
        for (int mi = 0; mi < 4; ++mi) {
            float v0 = fmaxf(acc[mi][ni][0] + bv[ni], 0.f);
            float v1 = fmaxf(acc[mi][ni][1] + bv[ni], 0.f);
            float v2 = fmaxf(acc[mi][ni][2] + bv[ni], 0.f);
            float v3 = fmaxf(acc[mi][ni][3] + bv[ni], 0.f);
            unsigned p01 = cvt_pk_bf16(v0, v1);
            unsigned p23 = cvt_pk_bf16(v2, v3);
            unsigned short* wb = (unsigned short*)hs
                + (mi * 16 + quad * 4) * LDH + n0 + ni * 16 + lq;
            wb[0]        = (unsigned short)p01;
            wb[LDH]      = (unsigned short)(p01 >> 16);
            wb[2 * LDH]  = (unsigned short)p23;
            wb[3 * LDH]  = (unsigned short)(p23 >> 16);
        }
    }
    __syncthreads();
}

__global__ __launch_bounds__(512, 4) void critic_kernel(
    const float* __restrict__ hx, const float* __restrict__ hy,
    const short* __restrict__ W1p, const short* __restrict__ W2p,
    const float* __restrict__ b1, const float* __restrict__ b2,
    const float* __restrict__ W3, const float* __restrict__ b3,
    float* __restrict__ out) {
    __shared__ short hs[MT * LDH];   // 66,560 B
    __shared__ float psum[64 * 9];   // 2,304 B (stride 9 breaks bank aliasing)

    const int tid = threadIdx.x;
    const int wave = tid >> 6;
    const int lane = tid & 63;
    const int quad = lane >> 4;
    const int lq   = lane & 15;

    const int i0 = (blockIdx.x >> 5) * 8;
    const int j0 = (blockIdx.x & 31) * 8;

    // ---- h0 = relu(hx[i] + hy[j]) bf16 in LDS (b0 folded into hx) ----
    #pragma unroll
    for (int e = tid; e < MT * 64; e += 512) {
        int r = e >> 6;
        int ko = (e & 63) * 8;
        int ti = r >> 3, tj = r & 7;
        const float4_t* px = (const float4_t*)(hx + (i0 + ti) * HID + ko);
        const float4_t* py = (const float4_t*)(hy + (j0 + tj) * HID + ko);
        float4_t a0 = px[0], a1 = px[1];
        float4_t c0 = py[0], c1 = py[1];
        unsigned d0 = cvt_pk_bf16(fmaxf(a0[0] + c0[0], 0.f), fmaxf(a0[1] + c0[1], 0.f));
        unsigned d1 = cvt_pk_bf16(fmaxf(a0[2] + c0[2], 0.f), fmaxf(a0[3] + c0[3], 0.f));
        unsigned d2 = cvt_pk_bf16(fmaxf(a1[0] + c1[0], 0.f), fmaxf(a1[1] + c1[1], 0.f));
        unsigned d3 = cvt_pk_bf16(fmaxf(a1[2] + c1[2], 0.f), fmaxf(a1[3] + c1[3], 0.f));
        *(uint4_t*)(hs + r * LDH + ko) = (uint4_t){d0, d1, d2, d3};
    }
    __syncthreads();

    gemm_layer(hs, W1p, b1, wave, lane);   // h1 = relu(h0 @ W1 + b1)
    gemm_layer(hs, W2p, b2, wave, lane);   // h2 = relu(h1 @ W2 + b2)

    // ---- final: out = h2 @ W3 + b3, via MFMA (B nonzero only in col 0) ----
    {
        const int n0 = wave * 64;
        // B-fragment for k-step s: B[k = s*32 + quad*8 + j][col = lq].
        // Only col 0 carries W3; other cols zero. One fragment PER k-step
        // (round-1 bug: a single fragment was reused for both s).
        union { unsigned u[4]; short8 v; } w3u[2];
        #pragma unroll
        for (int s = 0; s < 2; ++s) {
            float wv[8];
            #pragma unroll
            for (int j = 0; j < 8; ++j)
                wv[j] = (lq == 0) ? W3[n0 + s * 32 + quad * 8 + j] : 0.f;
            #pragma unroll
            for (int j = 0; j < 4; ++j)
                w3u[s].u[j] = cvt_pk_bf16(wv[2 * j], wv[2 * j + 1]);
        }

        float4_t facc[4];
        #pragma unroll
        for (int mi = 0; mi < 4; ++mi) facc[mi] = (float4_t){0.f, 0.f, 0.f, 0.f};

        const short* abase = hs + lq * LDH + n0 + quad * 8;
        #pragma unroll
        for (int s = 0; s < 2; ++s)
            #pragma unroll
            for (int mi = 0; mi < 4; ++mi) {
                short8 af = *(const short8*)(abase + mi * 16 * LDH + s * 32);
                facc[mi] = __builtin_amdgcn_mfma_f32_16x16x32_bf16(
                    af, w3u[s].v, facc[mi], 0, 0, 0);
            }

        // C/D: col = lane&15, row = quad*4 + r (+ mi*16). Col 0 lanes hold
        // this wave's partial (sum over its 64 h-cols) for all 64 rows.
        if (lq == 0) {
            #pragma unroll
            for (int mi = 0; mi < 4; ++mi)
                #pragma unroll
                for (int r = 0; r < 4; ++r)
                    psum[(mi * 16 + quad * 4 + r) * 9 + wave] = facc[mi][r];
        }
    }
    __syncthreads();
    if (tid < 64) {
        float s = b3[0];
        #pragma unroll
        for (int o = 0; o < 8; ++o) s += psum[tid * 9 + o];
        out[(i0 + (tid >> 3)) * BSZ + (j0 + (tid & 7))] = s;
    }
}

extern "C" void kernel_launch(void* const* d_in, const int* in_sizes, int n_in,
                              void* d_out, int out_size, void* d_ws, size_t ws_size,
                              hipStream_t stream) {
    const float* x  = (const float*)d_in[0];
    const float* y  = (const float*)d_in[1];
    const float* Wx = (const float*)d_in[2];
    const float* Wy = (const float*)d_in[3];
    const float* b0 = (const float*)d_in[4];
    const float* W1 = (const float*)d_in[5];
    const float* b1 = (const float*)d_in[6];
    const float* W2 = (const float*)d_in[7];
    const float* b2 = (const float*)d_in[8];
    const float* W3 = (const float*)d_in[9];
    const float* b3 = (const float*)d_in[10];
    float* out = (float*)d_out;

    char* ws = (char*)d_ws;
    float* hx  = (float*)(ws);
    float* hy  = (float*)(ws + 512 * 1024);
    short* W1p = (short*)(ws + 1024 * 1024);
    short* W2p = (short*)(ws + 1536 * 1024);

    prep_kernel<<<256, 512, 0, stream>>>(x, y, Wx, Wy, b0, W1, W2, hx, hy, W1p, W2p);
    critic_kernel<<<1024, 512, 0, stream>>>(hx, hy, W1p, W2p, b1, b2, W3, b3, out);
}